// Round 11
// baseline (19550.456 us; speedup 1.0000x reference)
//
#include <hip/hip_runtime.h>
#include <hip/hip_fp16.h>
#include <hip/hip_cooperative_groups.h>
#include <cstddef>
#include <cstdint>

namespace cg = cooperative_groups;

#define NSG   8
#define NPAIR 28
#define NBLK  36                 // unique cost products: 28 cross + 8 self
#define NPT   1024
#define DIM   256
#define NROW  8192
#define LOG_N  6.9314718055994531f
#define LOG2E  1.4426950408889634f

// triu_indices(8,1) pairs, then 8 self pairs
__constant__ int c_pa[NBLK] = {0,0,0,0,0,0,0,1,1,1,1,1,1,2,2,2,2,2,3,3,3,3,4,4,4,5,5,6, 0,1,2,3,4,5,6,7};
__constant__ int c_pb[NBLK] = {1,2,3,4,5,6,7,2,3,4,5,6,7,3,4,5,6,7,4,5,6,7,5,6,7,6,7,7, 0,1,2,3,4,5,6,7};

__device__ __forceinline__ float wredMax(float v) {
#pragma unroll
  for (int o = 32; o > 0; o >>= 1) v = fmaxf(v, __shfl_xor(v, o, 64));
  return v;
}
__device__ __forceinline__ float wredMin(float v) {
#pragma unroll
  for (int o = 32; o > 0; o >>= 1) v = fminf(v, __shfl_xor(v, o, 64));
  return v;
}
__device__ __forceinline__ float wredSum(float v) {
#pragma unroll
  for (int o = 32; o > 0; o >>= 1) v += __shfl_xor(v, o, 64);
  return v;
}

__device__ __forceinline__ void cvt16(float4 A, float4 B, float* c) {
  const __half2* ha = (const __half2*)&A;
  const __half2* hb = (const __half2*)&B;
#pragma unroll
  for (int i = 0; i < 4; i++) {
    float2 f = __half22float2(ha[i]);
    c[2 * i] = f.x; c[2 * i + 1] = f.y;
  }
#pragma unroll
  for (int i = 0; i < 4; i++) {
    float2 f = __half22float2(hb[i]);
    c[8 + 2 * i] = f.x; c[8 + 2 * i + 1] = f.y;
  }
}

__device__ __forceinline__ float ub(unsigned int w, int s) {
  return (float)((w >> s) & 0xffu);   // v_cvt_f32_ubyteN
}

// ---- phase 0: grouping ----
__global__ void build_idx(const int* __restrict__ sg, int* __restrict__ idx, int* __restrict__ cnt) {
  int i = blockIdx.x * 256 + threadIdx.x;
  if (i >= NROW) return;
  int s = sg[i];
  int r = atomicAdd(&cnt[s], 1);
  idx[s * NPT + r] = i;
}

__global__ void gather_rows(const float* __restrict__ feat, const int* __restrict__ idx,
                            float* __restrict__ G, float* __restrict__ sq) {
  int row = blockIdx.x;
  int src = idx[row];
  float v = feat[(size_t)src * DIM + threadIdx.x];
  G[(size_t)row * DIM + threadIdx.x] = v;
  float p = wredSum(v * v);
  __shared__ float ws[4];
  if ((threadIdx.x & 63) == 0) ws[threadIdx.x >> 6] = p;
  __syncthreads();
  if (threadIdx.x == 0) sq[row] = 0.5f * (ws[0] + ws[1] + ws[2] + ws[3]);
}

// ---- phase 1: cost matrices (fp16) into Ch[b], b = unique product idx ----
__global__ __launch_bounds__(256) void cost_gemm(const float* __restrict__ G,
                                                 const float* __restrict__ sq,
                                                 __half* __restrict__ Ch) {
  __shared__ float As[8][128];
  __shared__ float Bt[8][128];
  int blk = blockIdx.x;
  int b = blk >> 6, t = blk & 63;
  int sa = c_pa[b], sb = c_pb[b];
  int i0 = (t >> 3) << 7, j0 = (t & 7) << 7;
  const float* Arows = G + (size_t)(sa * NPT + i0) * DIM;
  const float* Brows = G + (size_t)(sb * NPT + j0) * DIM;
  int tid = threadIdx.x;
  int ty = tid >> 4, tx = tid & 15;
  float acc[8][8];
#pragma unroll
  for (int r = 0; r < 8; r++)
#pragma unroll
    for (int q = 0; q < 8; q++) acc[r][q] = 0.f;

  int lrow = tid >> 1, lk4 = (tid & 1) << 2;
  for (int k0 = 0; k0 < DIM; k0 += 8) {
    __syncthreads();
    float4 av = *(const float4*)(Arows + (size_t)lrow * DIM + k0 + lk4);
    float4 bv = *(const float4*)(Brows + (size_t)lrow * DIM + k0 + lk4);
    As[lk4 + 0][lrow] = av.x; As[lk4 + 1][lrow] = av.y; As[lk4 + 2][lrow] = av.z; As[lk4 + 3][lrow] = av.w;
    Bt[lk4 + 0][lrow] = bv.x; Bt[lk4 + 1][lrow] = bv.y; Bt[lk4 + 2][lrow] = bv.z; Bt[lk4 + 3][lrow] = bv.w;
    __syncthreads();
#pragma unroll
    for (int kk = 0; kk < 8; kk++) {
      float4 a0 = *(const float4*)&As[kk][ty << 3];
      float4 a1 = *(const float4*)&As[kk][(ty << 3) + 4];
      float4 b0 = *(const float4*)&Bt[kk][tx << 3];
      float4 b1 = *(const float4*)&Bt[kk][(tx << 3) + 4];
      float ar[8] = {a0.x, a0.y, a0.z, a0.w, a1.x, a1.y, a1.z, a1.w};
      float br[8] = {b0.x, b0.y, b0.z, b0.w, b1.x, b1.y, b1.z, b1.w};
#pragma unroll
      for (int r = 0; r < 8; r++)
#pragma unroll
        for (int q = 0; q < 8; q++) acc[r][q] = fmaf(ar[r], br[q], acc[r][q]);
    }
  }
  __half* dst = Ch + ((size_t)b << 20);
  float sqa[8], sqb[8];
#pragma unroll
  for (int r = 0; r < 8; r++) sqa[r] = sq[sa * NPT + i0 + (ty << 3) + r];
#pragma unroll
  for (int q = 0; q < 8; q++) sqb[q] = sq[sb * NPT + j0 + (tx << 3) + q];
#pragma unroll
  for (int r = 0; r < 8; r++) {
    __half* drow = dst + (size_t)(i0 + (ty << 3) + r) * NPT + j0 + (tx << 3);
    union { float4 f4; __half h[8]; } o;
#pragma unroll
    for (int q = 0; q < 8; q++)
      o.h[q] = __float2half_rn(fmaxf(sqa[r] + sqb[q] - acc[r][q], 0.f));
    *(float4*)drow = o.f4;
  }
}

// ---- phase 1b: per-row u8 quantization into C8 slot (q = 8a+b layout; diag = 9a) ----
__global__ __launch_bounds__(256) void quant_row(const __half* __restrict__ Ch,
                                                 unsigned char* __restrict__ C8,
                                                 float2* __restrict__ rowScale) {
  const int blk = blockIdx.x;
  const int b = blk >> 4, rowblk = blk & 15;
  const int sa = c_pa[b], sb = c_pb[b];
  const int q = (sa == sb) ? 9 * sa : 8 * sa + sb;
  const __half* src = Ch + ((size_t)b << 20);
  unsigned char* dst = C8 + ((size_t)q << 20);
  const int wave = threadIdx.x >> 6, lane = threadIdx.x & 63;
  for (int jj = 0; jj < 16; jj++) {
    const int row = (rowblk << 6) + (jj << 2) + wave;
    const float4* s4 = (const float4*)(src + ((size_t)row << 10) + (lane << 4));
    float c[16];
    cvt16(s4[0], s4[1], c);
    float mn = c[0], mx = c[0];
#pragma unroll
    for (int t = 1; t < 16; t++) { mn = fminf(mn, c[t]); mx = fmaxf(mx, c[t]); }
    mn = wredMin(mn);
    mx = wredMax(mx);
    const float range = mx - mn;
    const float scale = (range > 1e-6f) ? range * (1.0f / 255.0f) : 1.0f;
    const float inv = (range > 1e-6f) ? 255.0f / range : 0.0f;
    unsigned int w[4];
#pragma unroll
    for (int d = 0; d < 4; d++) {
      unsigned int u0 = min(__float2uint_rn((c[4 * d + 0] - mn) * inv), 255u);
      unsigned int u1 = min(__float2uint_rn((c[4 * d + 1] - mn) * inv), 255u);
      unsigned int u2 = min(__float2uint_rn((c[4 * d + 2] - mn) * inv), 255u);
      unsigned int u3 = min(__float2uint_rn((c[4 * d + 3] - mn) * inv), 255u);
      w[d] = u0 | (u1 << 8) | (u2 << 16) | (u3 << 24);
    }
    *(uint4*)(dst + ((size_t)row << 10) + (lane << 4)) = make_uint4(w[0], w[1], w[2], w[3]);
    if (lane == 0) rowScale[(q << 10) + row] = make_float2(mn, scale);
  }
}

// ---- phase 1c: column stats for the transposed copies ----
__global__ __launch_bounds__(256) void colminmax(const __half* __restrict__ Ch,
                                                 float4* __restrict__ pMn, float4* __restrict__ pMx) {
  const int blk = blockIdx.x;
  const int p = blk >> 3, rb = blk & 7;
  const int j0 = threadIdx.x << 2;
  const __half* src = Ch + ((size_t)p << 20) + j0;
  float mn[4] = {3.4e38f, 3.4e38f, 3.4e38f, 3.4e38f};
  float mx[4] = {-3.4e38f, -3.4e38f, -3.4e38f, -3.4e38f};
  for (int r = 0; r < 128; r++) {
    const int row = (rb << 7) + r;
    uint2 raw = *(const uint2*)(src + ((size_t)row << 10));
    const __half2* hh = (const __half2*)&raw;
    float2 f0 = __half22float2(hh[0]);
    float2 f1 = __half22float2(hh[1]);
    float v[4] = {f0.x, f0.y, f1.x, f1.y};
#pragma unroll
    for (int t = 0; t < 4; t++) { mn[t] = fminf(mn[t], v[t]); mx[t] = fmaxf(mx[t], v[t]); }
  }
  const int o = ((p << 3) + rb) * 256 + threadIdx.x;
  pMn[o] = make_float4(mn[0], mn[1], mn[2], mn[3]);
  pMx[o] = make_float4(mx[0], mx[1], mx[2], mx[3]);
}

__global__ void colreduce(const float4* __restrict__ pMn, const float4* __restrict__ pMx,
                          float2* __restrict__ rowScale) {
  const int id = blockIdx.x * 256 + threadIdx.x;   // 28*256
  const int p = id >> 8, t = id & 255;
  float4 mn = pMn[(p << 3) * 256 + t];
  float4 mx = pMx[(p << 3) * 256 + t];
  for (int rb = 1; rb < 8; rb++) {
    float4 a = pMn[((p << 3) + rb) * 256 + t];
    float4 b = pMx[((p << 3) + rb) * 256 + t];
    mn.x = fminf(mn.x, a.x); mn.y = fminf(mn.y, a.y); mn.z = fminf(mn.z, a.z); mn.w = fminf(mn.w, a.w);
    mx.x = fmaxf(mx.x, b.x); mx.y = fmaxf(mx.y, b.y); mx.z = fmaxf(mx.z, b.z); mx.w = fmaxf(mx.w, b.w);
  }
  const int qT = 8 * c_pb[p] + c_pa[p];
  float bs[4] = {mn.x, mn.y, mn.z, mn.w};
  float xs[4] = {mx.x, mx.y, mx.z, mx.w};
#pragma unroll
  for (int cc = 0; cc < 4; cc++) {
    float range = xs[cc] - bs[cc];
    float scale = (range > 1e-6f) ? range * (1.0f / 255.0f) : 1.0f;
    rowScale[(qT << 10) + (t << 2) + cc] = make_float2(bs[cc], scale);
  }
}

// ---- phase 1d: transpose + quantize into the mate slot ----
__global__ __launch_bounds__(256) void quantT(const __half* __restrict__ Ch,
                                              const float2* __restrict__ rowScale,
                                              unsigned char* __restrict__ C8) {
  __shared__ __half t[64][72];
  const int blk = blockIdx.x;            // p*256 + tile
  const int p = blk >> 8, tb = blk & 255;
  const int i0 = (tb >> 4) << 6, j0 = (tb & 15) << 6;
  const int qT = 8 * c_pb[p] + c_pa[p];
  const __half* src = Ch + ((size_t)p << 20);
  unsigned char* dst = C8 + ((size_t)qT << 20);
  const int tid = threadIdx.x;
  const int r = tid >> 2, cg2 = (tid & 3) << 4;
  const float4* s4 = (const float4*)(src + ((size_t)(i0 + r) << 10) + j0 + cg2);
  float4 v0 = s4[0], v1 = s4[1];
  *(float4*)&t[r][cg2] = v0;
  *(float4*)&t[r][cg2 + 8] = v1;
  __syncthreads();
  const int jr = j0 + r;                 // dest row
  const float2 sc = rowScale[(qT << 10) + jr];
  const float inv = 1.0f / sc.y;
  unsigned int w[4];
#pragma unroll
  for (int d = 0; d < 4; d++) {
    unsigned int uu[4];
#pragma unroll
    for (int e = 0; e < 4; e++) {
      float c = __half2float(t[cg2 + 4 * d + e][r]);
      uu[e] = min(__float2uint_rn((c - sc.x) * inv), 255u);
    }
    w[d] = uu[0] | (uu[1] << 8) | (uu[2] << 16) | (uu[3] << 24);
  }
  *(uint4*)(dst + ((size_t)jr << 10) + i0 + cg2) = make_uint4(w[0], w[1], w[2], w[3]);
}

// ---- epsilon schedule on-device (bit-identical to the host double recurrence) ----
__global__ void sched_init(float* __restrict__ s) {
  if (threadIdx.x == 0 && blockIdx.x == 0) {
    double e = 256.0;
    const double ratio = 0.9 * 0.9;
    const double tgt = 1e-4 * 1e-4;
    int n = 0;
    while (e > tgt) { s[n++] = (float)e; e *= ratio; }
    s[n] = (float)tgt;   // n == 114 -> 115 entries total
  }
}

// ---- phase 2a: the ENTIRE scan in one persistent cooperative kernel ----
// 1024 blocks x 512 threads = full-device co-residency (4 blocks/CU, 32 waves/CU).
// Each thread owns 128 B of C8 in registers (uv[8]) for ALL 116 steps.
__global__ __launch_bounds__(512, 8) void sink_scan(
    const unsigned char* __restrict__ C8, const float2* __restrict__ rowScale,
    const float* __restrict__ sched, float* pot0, float* pot1) {
  cg::grid_group grid = cg::this_grid();
  __shared__ float2 ldsRS[64];
  const int b = blockIdx.x;
  const int x = b & 7, rr = b >> 3;
  const int q = ((rr & 7) << 3) | x;     // XCD swizzle
  const int chunk = rr >> 3;             // 0..15 (64-row chunks)
  const int mate = ((q & 7) << 3) | (q >> 3);
  const bool diag = (mate == q);
  const int wave = threadIdx.x >> 6, lane = threadIdx.x & 63;
  const int row0 = chunk << 6;

  if (threadIdx.x < 64)
    ldsRS[threadIdx.x] = rowScale[(q << 10) + row0 + threadIdx.x];

  // load this thread's 8 C-rows (16 B each) ONCE for the whole scan
  const unsigned char* Cb = C8 + ((size_t)q << 20) + ((size_t)row0 << 10) + (lane << 4);
  uint4 uv[8];
#pragma unroll
  for (int k = 0; k < 8; k++)
    uv[k] = *(const uint4*)(Cb + ((size_t)((k << 3) + wave) << 10));
  __syncthreads();

  float* pc = pot0;
  float* pn = pot1;

  for (int st = 0; st < 116; st++) {
    const float eps = sched[st < 115 ? st : 114];
    const bool lse = (eps >= 1e-3f);
    const float cs = (diag && st != 115) ? 0.5f : 0.f;
    const float cm = diag ? ((st == 115) ? 1.f : 0.5f) : 1.f;
    const float c0 = LOG2E / eps;

    const float* hb = pc + (mate << 10) + (lane << 4);
    float h[16];
    {
      float4 h0 = ((const float4*)hb)[0], h1 = ((const float4*)hb)[1];
      float4 h2 = ((const float4*)hb)[2], h3 = ((const float4*)hb)[3];
      h[0]=h0.x; h[1]=h0.y; h[2]=h0.z; h[3]=h0.w;
      h[4]=h1.x; h[5]=h1.y; h[6]=h1.z; h[7]=h1.w;
      h[8]=h2.x; h[9]=h2.y; h[10]=h2.z; h[11]=h2.w;
      h[12]=h3.x; h[13]=h3.y; h[14]=h3.z; h[15]=h3.w;
    }

#pragma unroll
    for (int k = 0; k < 8; k++) {
      const int row = row0 + (k << 3) + wave;
      const float2 rs = ldsRS[(k << 3) + wave];
      const float ns = -rs.y;
      float m = -3.4e38f;
#pragma unroll
      for (int d = 0; d < 4; d++) {
        const unsigned int w = (&uv[k].x)[d];
        m = fmaxf(m, fmaf(ub(w, 0),  ns, h[4 * d + 0] - rs.x));
        m = fmaxf(m, fmaf(ub(w, 8),  ns, h[4 * d + 1] - rs.x));
        m = fmaxf(m, fmaf(ub(w, 16), ns, h[4 * d + 2] - rs.x));
        m = fmaxf(m, fmaf(ub(w, 24), ns, h[4 * d + 3] - rs.x));
      }
      m = wredMax(m);
      float sm;
      if (lse) {
        float ss = 0.f;
#pragma unroll
        for (int d = 0; d < 4; d++) {
          const unsigned int w = (&uv[k].x)[d];
          ss += exp2f((fmaf(ub(w, 0),  ns, h[4 * d + 0] - rs.x) - m) * c0);
          ss += exp2f((fmaf(ub(w, 8),  ns, h[4 * d + 1] - rs.x) - m) * c0);
          ss += exp2f((fmaf(ub(w, 16), ns, h[4 * d + 2] - rs.x) - m) * c0);
          ss += exp2f((fmaf(ub(w, 24), ns, h[4 * d + 3] - rs.x) - m) * c0);
        }
        ss = wredSum(ss);
        sm = -(m + eps * (__logf(ss) - LOG_N));
      } else {
        sm = -m;   // softmin -> min as eps -> 0; |err| <= eps*log n
      }
      if (lane == 0)
        pn[(q << 10) + row] = cs * pc[(q << 10) + row] + cm * sm;
    }

    grid.sync();
    float* t = pc; pc = pn; pn = t;
  }
  // 116 steps (even): final potentials land in pot0
}

// ---- phase 2b: per-step fallback (identical math; used only if coop launch is rejected) ----
template <bool LSE>
__global__ __launch_bounds__(256) void sink_step(
    const unsigned char* __restrict__ C8, const float2* __restrict__ rowScale,
    const float* __restrict__ pot_cur, float* __restrict__ pot_nxt,
    float eps, float csS, float cmS) {
  const int i = blockIdx.x;
  const int x = i & 7, rr = i >> 3;
  const int q = ((rr & 7) << 3) | x;
  const int chunk = rr >> 3;
  const int mate = ((q & 7) << 3) | (q >> 3);
  const bool diag = (mate == q);
  const float cs = diag ? csS : 0.f;
  const float cm = diag ? cmS : 1.f;
  const int wave = threadIdx.x >> 6, lane = threadIdx.x & 63;
  const float* hp = pot_cur + (mate << 10) + (lane << 4);
  float h[16];
  {
    float4 h0 = ((const float4*)hp)[0], h1 = ((const float4*)hp)[1];
    float4 h2 = ((const float4*)hp)[2], h3 = ((const float4*)hp)[3];
    h[0]=h0.x; h[1]=h0.y; h[2]=h0.z; h[3]=h0.w;
    h[4]=h1.x; h[5]=h1.y; h[6]=h1.z; h[7]=h1.w;
    h[8]=h2.x; h[9]=h2.y; h[10]=h2.z; h[11]=h2.w;
    h[12]=h3.x; h[13]=h3.y; h[14]=h3.z; h[15]=h3.w;
  }
  const float c0 = LOG2E / eps;
  const unsigned char* Cb = C8 + ((size_t)q << 20) + ((size_t)chunk << 15) + (lane << 4);
  uint4 uv[8];
#pragma unroll
  for (int k = 0; k < 8; k++)
    uv[k] = *(const uint4*)(Cb + ((size_t)((k << 2) + wave) << 10));
#pragma unroll
  for (int k = 0; k < 8; k++) {
    const int row = (chunk << 5) + (k << 2) + wave;
    const float2 rs = rowScale[(q << 10) + row];
    const float ns = -rs.y;
    float a[16];
#pragma unroll
    for (int d = 0; d < 4; d++) {
      const unsigned int w = (&uv[k].x)[d];
      a[4 * d + 0] = fmaf(ub(w, 0),  ns, h[4 * d + 0] - rs.x);
      a[4 * d + 1] = fmaf(ub(w, 8),  ns, h[4 * d + 1] - rs.x);
      a[4 * d + 2] = fmaf(ub(w, 16), ns, h[4 * d + 2] - rs.x);
      a[4 * d + 3] = fmaf(ub(w, 24), ns, h[4 * d + 3] - rs.x);
    }
    float m = a[0];
#pragma unroll
    for (int t = 1; t < 16; t++) m = fmaxf(m, a[t]);
    m = wredMax(m);
    float sm;
    if (LSE) {
      float ss = 0.f;
#pragma unroll
      for (int t = 0; t < 16; t++) ss += exp2f((a[t] - m) * c0);
      ss = wredSum(ss);
      sm = -(m + eps * (__logf(ss) - LOG_N));
    } else {
      sm = -m;
    }
    if (lane == 0)
      pot_nxt[(q << 10) + row] = cs * pot_cur[(q << 10) + row] + cm * sm;
  }
}

// ---- phase 3: losses ----
__global__ void loss_pairs(const float* __restrict__ pot, float* __restrict__ out) {
  int pb = blockIdx.x;
  int si = c_pa[pb], sj = c_pb[pb];
  const float* fv = pot + ((8 * si + sj) << 10);
  const float* gv = pot + ((8 * sj + si) << 10);
  const float* sa = pot + ((9 * si) << 10);
  const float* sb = pot + ((9 * sj) << 10);
  float acc = 0.f;
  for (int t = threadIdx.x; t < NPT; t += 256)
    acc += (fv[t] - sa[t]) + (gv[t] - sb[t]);
  acc = wredSum(acc);
  __shared__ float wsm[4];
  if ((threadIdx.x & 63) == 0) wsm[threadIdx.x >> 6] = acc;
  __syncthreads();
  if (threadIdx.x == 0) out[1 + pb] = (wsm[0] + wsm[1] + wsm[2] + wsm[3]) * (1.0f / NPT);
}

__global__ void loss_total(float* __restrict__ out) {
  int t = threadIdx.x;
  float x = (t < NPAIR) ? out[1 + t] : 0.f;
  x = wredSum(x);
  if (t == 0) out[0] = x / (float)NPAIR;
}

extern "C" void kernel_launch(void* const* d_in, const int* in_sizes, int n_in,
                              void* d_out, int out_size, void* d_ws, size_t ws_size,
                              hipStream_t stream) {
  const float* feat = (const float*)d_in[0];
  const int* sg = (const int*)d_in[1];
  float* out = (float*)d_out;
  char* ws = (char*)d_ws;

  size_t o = 0;
  __half* Ch = (__half*)(ws + o); o += (size_t)NBLK * NPT * NPT * 2;      // 72 MB (fp16 staging)
  unsigned char* C8 = (unsigned char*)(ws + o); o += (size_t)64 * NPT * NPT; // 64 MB (u8, both orientations)
  float2* rowScale = (float2*)(ws + o); o += (size_t)64 * NPT * 8;        // 512 KB
  float4* pMn = (float4*)(ws + o); o += (size_t)NPAIR * 8 * 256 * 16;     // 0.9 MB
  float4* pMx = (float4*)(ws + o); o += (size_t)NPAIR * 8 * 256 * 16;
  float* G  = (float*)(ws + o); o += (size_t)NROW * DIM * 4;              // 8.4 MB
  float* sq = (float*)(ws + o); o += (size_t)NROW * 4;
  int* idx  = (int*)(ws + o); o += (size_t)NROW * 4;
  int* cnt  = (int*)(ws + o); o += 1024;
  float* schedDev = (float*)(ws + o); o += 512;
  float* pot0 = (float*)(ws + o); o += (size_t)64 * NPT * 4;
  float* pot1 = (float*)(ws + o); o += (size_t)64 * NPT * 4;

  hipMemsetAsync(cnt, 0, 1024, stream);
  hipMemsetAsync(pot0, 0, (size_t)64 * NPT * 4, stream);   // f0=g0=s0=0

  build_idx<<<NROW / 256, 256, 0, stream>>>(sg, idx, cnt);
  gather_rows<<<NROW, 256, 0, stream>>>(feat, idx, G, sq);
  cost_gemm<<<NBLK * 64, 256, 0, stream>>>(G, sq, Ch);
  quant_row<<<NBLK * 16, 256, 0, stream>>>(Ch, C8, rowScale);
  colminmax<<<NPAIR * 8, 256, 0, stream>>>(Ch, pMn, pMx);
  colreduce<<<NPAIR, 256, 0, stream>>>(pMn, pMx, rowScale);
  quantT<<<NPAIR * 256, 256, 0, stream>>>(Ch, rowScale, C8);
  sched_init<<<1, 64, 0, stream>>>(schedDev);

  // host copy of the schedule (identical recurrence) for the fallback path
  float sched[256];
  int ns = 0;
  {
    double e = 256.0;
    const double ratio = 0.9 * 0.9;
    const double tgt = 1e-4 * 1e-4;
    while (e > tgt) { sched[ns++] = (float)e; e *= ratio; }
    sched[ns++] = (float)tgt;   // ns == 115
  }
  const float epsT = sched[ns - 1];

  // try the single cooperative launch (whole scan, C in registers)
  void* args[] = {(void*)&C8, (void*)&rowScale, (void*)&schedDev, (void*)&pot0, (void*)&pot1};
  hipError_t cerr = hipLaunchCooperativeKernel((void*)sink_scan, dim3(1024), dim3(512),
                                               args, 0, stream);
  if (cerr != hipSuccess) {
    (void)hipGetLastError();   // clear sticky error, fall back to per-step kernels
    float* pp[2] = {pot0, pot1};
    int cur = 0;
    for (int k = 0; k < ns; k++) {
      if (sched[k] >= 1e-3f)
        sink_step<true><<<64 * 32, 256, 0, stream>>>(C8, rowScale, pp[cur], pp[1 - cur],
                                                     sched[k], 0.5f, 0.5f);
      else
        sink_step<false><<<64 * 32, 256, 0, stream>>>(C8, rowScale, pp[cur], pp[1 - cur],
                                                      sched[k], 0.5f, 0.5f);
      cur ^= 1;
    }
    sink_step<false><<<64 * 32, 256, 0, stream>>>(C8, rowScale, pp[cur], pp[1 - cur],
                                                  epsT, 0.0f, 1.0f);
    // 116 launches total -> final potentials in pot0 (same as coop path)
  }

  loss_pairs<<<NPAIR, 256, 0, stream>>>(pot0, out);
  loss_total<<<1, 64, 0, stream>>>(out);
}

// Round 12
// 13760.446 us; speedup vs baseline: 1.4208x; 1.4208x over previous
//
#include <hip/hip_runtime.h>
#include <hip/hip_fp16.h>
#include <cstddef>
#include <cstdint>

#define NSG   8
#define NPAIR 28
#define NBLK  36                 // unique cost products: 28 cross + 8 self
#define NPT   1024
#define DIM   256
#define NROW  8192
#define LOG_N  6.9314718055994531f
#define LOG2E  1.4426950408889634f

// triu_indices(8,1) pairs, then 8 self pairs
__constant__ int c_pa[NBLK] = {0,0,0,0,0,0,0,1,1,1,1,1,1,2,2,2,2,2,3,3,3,3,4,4,4,5,5,6, 0,1,2,3,4,5,6,7};
__constant__ int c_pb[NBLK] = {1,2,3,4,5,6,7,2,3,4,5,6,7,3,4,5,6,7,4,5,6,7,5,6,7,6,7,7, 0,1,2,3,4,5,6,7};
// family id for slot q=8a+b: cross pair index (a<b ordering) or 28+a for diag
__constant__ int c_fam[64] = {
  28, 0, 1, 2, 3, 4, 5, 6,
   0,29, 7, 8, 9,10,11,12,
   1, 7,30,13,14,15,16,17,
   2, 8,13,31,18,19,20,21,
   3, 9,14,18,32,22,23,24,
   4,10,15,19,22,33,25,26,
   5,11,16,20,23,25,34,27,
   6,12,17,21,24,26,27,35};

__device__ __forceinline__ float wredMax(float v) {
#pragma unroll
  for (int o = 32; o > 0; o >>= 1) v = fmaxf(v, __shfl_xor(v, o, 64));
  return v;
}
__device__ __forceinline__ float wredMin(float v) {
#pragma unroll
  for (int o = 32; o > 0; o >>= 1) v = fminf(v, __shfl_xor(v, o, 64));
  return v;
}
__device__ __forceinline__ float wredSum(float v) {
#pragma unroll
  for (int o = 32; o > 0; o >>= 1) v += __shfl_xor(v, o, 64);
  return v;
}

__device__ __forceinline__ void cvt16(float4 A, float4 B, float* c) {
  const __half2* ha = (const __half2*)&A;
  const __half2* hb = (const __half2*)&B;
#pragma unroll
  for (int i = 0; i < 4; i++) {
    float2 f = __half22float2(ha[i]);
    c[2 * i] = f.x; c[2 * i + 1] = f.y;
  }
#pragma unroll
  for (int i = 0; i < 4; i++) {
    float2 f = __half22float2(hb[i]);
    c[8 + 2 * i] = f.x; c[8 + 2 * i + 1] = f.y;
  }
}

__device__ __forceinline__ float ub(unsigned int w, int s) {
  return (float)((w >> s) & 0xffu);   // v_cvt_f32_ubyteN
}

// inline family barrier: monotonic counter, no reset, no ABI call -> no spills
__device__ __forceinline__ void famsync(int* cnt, int target) {
  __syncthreads();
  if (threadIdx.x == 0) {
    __threadfence();  // release: pot writes visible device-wide
    __hip_atomic_fetch_add(cnt, 1, __ATOMIC_ACQ_REL, __HIP_MEMORY_SCOPE_AGENT);
    while (__hip_atomic_load(cnt, __ATOMIC_ACQUIRE, __HIP_MEMORY_SCOPE_AGENT) < target)
      __builtin_amdgcn_s_sleep(1);
    __threadfence();  // acquire: invalidate L1 so pot reads are fresh
  }
  __syncthreads();
}

// ---- phase 0: grouping ----
__global__ void build_idx(const int* __restrict__ sg, int* __restrict__ idx, int* __restrict__ cnt) {
  int i = blockIdx.x * 256 + threadIdx.x;
  if (i >= NROW) return;
  int s = sg[i];
  int r = atomicAdd(&cnt[s], 1);
  idx[s * NPT + r] = i;
}

__global__ void gather_rows(const float* __restrict__ feat, const int* __restrict__ idx,
                            float* __restrict__ G, float* __restrict__ sq) {
  int row = blockIdx.x;
  int src = idx[row];
  float v = feat[(size_t)src * DIM + threadIdx.x];
  G[(size_t)row * DIM + threadIdx.x] = v;
  float p = wredSum(v * v);
  __shared__ float ws[4];
  if ((threadIdx.x & 63) == 0) ws[threadIdx.x >> 6] = p;
  __syncthreads();
  if (threadIdx.x == 0) sq[row] = 0.5f * (ws[0] + ws[1] + ws[2] + ws[3]);
}

// ---- phase 1: cost matrices (fp16) into Ch[b], b = unique product idx ----
__global__ __launch_bounds__(256) void cost_gemm(const float* __restrict__ G,
                                                 const float* __restrict__ sq,
                                                 __half* __restrict__ Ch) {
  __shared__ float As[8][128];
  __shared__ float Bt[8][128];
  int blk = blockIdx.x;
  int b = blk >> 6, t = blk & 63;
  int sa = c_pa[b], sb = c_pb[b];
  int i0 = (t >> 3) << 7, j0 = (t & 7) << 7;
  const float* Arows = G + (size_t)(sa * NPT + i0) * DIM;
  const float* Brows = G + (size_t)(sb * NPT + j0) * DIM;
  int tid = threadIdx.x;
  int ty = tid >> 4, tx = tid & 15;
  float acc[8][8];
#pragma unroll
  for (int r = 0; r < 8; r++)
#pragma unroll
    for (int q = 0; q < 8; q++) acc[r][q] = 0.f;

  int lrow = tid >> 1, lk4 = (tid & 1) << 2;
  for (int k0 = 0; k0 < DIM; k0 += 8) {
    __syncthreads();
    float4 av = *(const float4*)(Arows + (size_t)lrow * DIM + k0 + lk4);
    float4 bv = *(const float4*)(Brows + (size_t)lrow * DIM + k0 + lk4);
    As[lk4 + 0][lrow] = av.x; As[lk4 + 1][lrow] = av.y; As[lk4 + 2][lrow] = av.z; As[lk4 + 3][lrow] = av.w;
    Bt[lk4 + 0][lrow] = bv.x; Bt[lk4 + 1][lrow] = bv.y; Bt[lk4 + 2][lrow] = bv.z; Bt[lk4 + 3][lrow] = bv.w;
    __syncthreads();
#pragma unroll
    for (int kk = 0; kk < 8; kk++) {
      float4 a0 = *(const float4*)&As[kk][ty << 3];
      float4 a1 = *(const float4*)&As[kk][(ty << 3) + 4];
      float4 b0 = *(const float4*)&Bt[kk][tx << 3];
      float4 b1 = *(const float4*)&Bt[kk][(tx << 3) + 4];
      float ar[8] = {a0.x, a0.y, a0.z, a0.w, a1.x, a1.y, a1.z, a1.w};
      float br[8] = {b0.x, b0.y, b0.z, b0.w, b1.x, b1.y, b1.z, b1.w};
#pragma unroll
      for (int r = 0; r < 8; r++)
#pragma unroll
        for (int q = 0; q < 8; q++) acc[r][q] = fmaf(ar[r], br[q], acc[r][q]);
    }
  }
  __half* dst = Ch + ((size_t)b << 20);
  float sqa[8], sqb[8];
#pragma unroll
  for (int r = 0; r < 8; r++) sqa[r] = sq[sa * NPT + i0 + (ty << 3) + r];
#pragma unroll
  for (int q = 0; q < 8; q++) sqb[q] = sq[sb * NPT + j0 + (tx << 3) + q];
#pragma unroll
  for (int r = 0; r < 8; r++) {
    __half* drow = dst + (size_t)(i0 + (ty << 3) + r) * NPT + j0 + (tx << 3);
    union { float4 f4; __half h[8]; } o;
#pragma unroll
    for (int q = 0; q < 8; q++)
      o.h[q] = __float2half_rn(fmaxf(sqa[r] + sqb[q] - acc[r][q], 0.f));
    *(float4*)drow = o.f4;
  }
}

// ---- phase 1b: per-row u8 quantization into C8 slot (q = 8a+b layout; diag = 9a) ----
__global__ __launch_bounds__(256) void quant_row(const __half* __restrict__ Ch,
                                                 unsigned char* __restrict__ C8,
                                                 float2* __restrict__ rowScale) {
  const int blk = blockIdx.x;
  const int b = blk >> 4, rowblk = blk & 15;
  const int sa = c_pa[b], sb = c_pb[b];
  const int q = (sa == sb) ? 9 * sa : 8 * sa + sb;
  const __half* src = Ch + ((size_t)b << 20);
  unsigned char* dst = C8 + ((size_t)q << 20);
  const int wave = threadIdx.x >> 6, lane = threadIdx.x & 63;
  for (int jj = 0; jj < 16; jj++) {
    const int row = (rowblk << 6) + (jj << 2) + wave;
    const float4* s4 = (const float4*)(src + ((size_t)row << 10) + (lane << 4));
    float c[16];
    cvt16(s4[0], s4[1], c);
    float mn = c[0], mx = c[0];
#pragma unroll
    for (int t = 1; t < 16; t++) { mn = fminf(mn, c[t]); mx = fmaxf(mx, c[t]); }
    mn = wredMin(mn);
    mx = wredMax(mx);
    const float range = mx - mn;
    const float scale = (range > 1e-6f) ? range * (1.0f / 255.0f) : 1.0f;
    const float inv = (range > 1e-6f) ? 255.0f / range : 0.0f;
    unsigned int w[4];
#pragma unroll
    for (int d = 0; d < 4; d++) {
      unsigned int u0 = min(__float2uint_rn((c[4 * d + 0] - mn) * inv), 255u);
      unsigned int u1 = min(__float2uint_rn((c[4 * d + 1] - mn) * inv), 255u);
      unsigned int u2 = min(__float2uint_rn((c[4 * d + 2] - mn) * inv), 255u);
      unsigned int u3 = min(__float2uint_rn((c[4 * d + 3] - mn) * inv), 255u);
      w[d] = u0 | (u1 << 8) | (u2 << 16) | (u3 << 24);
    }
    *(uint4*)(dst + ((size_t)row << 10) + (lane << 4)) = make_uint4(w[0], w[1], w[2], w[3]);
    if (lane == 0) rowScale[(q << 10) + row] = make_float2(mn, scale);
  }
}

// ---- phase 1c: column stats for the transposed copies ----
__global__ __launch_bounds__(256) void colminmax(const __half* __restrict__ Ch,
                                                 float4* __restrict__ pMn, float4* __restrict__ pMx) {
  const int blk = blockIdx.x;
  const int p = blk >> 3, rb = blk & 7;
  const int j0 = threadIdx.x << 2;
  const __half* src = Ch + ((size_t)p << 20) + j0;
  float mn[4] = {3.4e38f, 3.4e38f, 3.4e38f, 3.4e38f};
  float mx[4] = {-3.4e38f, -3.4e38f, -3.4e38f, -3.4e38f};
  for (int r = 0; r < 128; r++) {
    const int row = (rb << 7) + r;
    uint2 raw = *(const uint2*)(src + ((size_t)row << 10));
    const __half2* hh = (const __half2*)&raw;
    float2 f0 = __half22float2(hh[0]);
    float2 f1 = __half22float2(hh[1]);
    float v[4] = {f0.x, f0.y, f1.x, f1.y};
#pragma unroll
    for (int t = 0; t < 4; t++) { mn[t] = fminf(mn[t], v[t]); mx[t] = fmaxf(mx[t], v[t]); }
  }
  const int o = ((p << 3) + rb) * 256 + threadIdx.x;
  pMn[o] = make_float4(mn[0], mn[1], mn[2], mn[3]);
  pMx[o] = make_float4(mx[0], mx[1], mx[2], mx[3]);
}

__global__ void colreduce(const float4* __restrict__ pMn, const float4* __restrict__ pMx,
                          float2* __restrict__ rowScale) {
  const int id = blockIdx.x * 256 + threadIdx.x;   // 28*256
  const int p = id >> 8, t = id & 255;
  float4 mn = pMn[(p << 3) * 256 + t];
  float4 mx = pMx[(p << 3) * 256 + t];
  for (int rb = 1; rb < 8; rb++) {
    float4 a = pMn[((p << 3) + rb) * 256 + t];
    float4 b = pMx[((p << 3) + rb) * 256 + t];
    mn.x = fminf(mn.x, a.x); mn.y = fminf(mn.y, a.y); mn.z = fminf(mn.z, a.z); mn.w = fminf(mn.w, a.w);
    mx.x = fmaxf(mx.x, b.x); mx.y = fmaxf(mx.y, b.y); mx.z = fmaxf(mx.z, b.z); mx.w = fmaxf(mx.w, b.w);
  }
  const int qT = 8 * c_pb[p] + c_pa[p];
  float bs[4] = {mn.x, mn.y, mn.z, mn.w};
  float xs[4] = {mx.x, mx.y, mx.z, mx.w};
#pragma unroll
  for (int cc = 0; cc < 4; cc++) {
    float range = xs[cc] - bs[cc];
    float scale = (range > 1e-6f) ? range * (1.0f / 255.0f) : 1.0f;
    rowScale[(qT << 10) + (t << 2) + cc] = make_float2(bs[cc], scale);
  }
}

// ---- phase 1d: transpose + quantize into the mate slot ----
__global__ __launch_bounds__(256) void quantT(const __half* __restrict__ Ch,
                                              const float2* __restrict__ rowScale,
                                              unsigned char* __restrict__ C8) {
  __shared__ __half t[64][72];
  const int blk = blockIdx.x;            // p*256 + tile
  const int p = blk >> 8, tb = blk & 255;
  const int i0 = (tb >> 4) << 6, j0 = (tb & 15) << 6;
  const int qT = 8 * c_pb[p] + c_pa[p];
  const __half* src = Ch + ((size_t)p << 20);
  unsigned char* dst = C8 + ((size_t)qT << 20);
  const int tid = threadIdx.x;
  const int r = tid >> 2, cg2 = (tid & 3) << 4;
  const float4* s4 = (const float4*)(src + ((size_t)(i0 + r) << 10) + j0 + cg2);
  float4 v0 = s4[0], v1 = s4[1];
  *(float4*)&t[r][cg2] = v0;
  *(float4*)&t[r][cg2 + 8] = v1;
  __syncthreads();
  const int jr = j0 + r;                 // dest row
  const float2 sc = rowScale[(qT << 10) + jr];
  const float inv = 1.0f / sc.y;
  unsigned int w[4];
#pragma unroll
  for (int d = 0; d < 4; d++) {
    unsigned int uu[4];
#pragma unroll
    for (int e = 0; e < 4; e++) {
      float c = __half2float(t[cg2 + 4 * d + e][r]);
      uu[e] = min(__float2uint_rn((c - sc.x) * inv), 255u);
    }
    w[d] = uu[0] | (uu[1] << 8) | (uu[2] << 16) | (uu[3] << 24);
  }
  *(uint4*)(dst + ((size_t)jr << 10) + i0 + cg2) = make_uint4(w[0], w[1], w[2], w[3]);
}

// ---- epsilon schedule on-device (bit-identical to the host double recurrence) ----
__global__ void sched_init(float* __restrict__ s) {
  if (threadIdx.x == 0 && blockIdx.x == 0) {
    double e = 256.0;
    const double ratio = 0.9 * 0.9;
    const double tgt = 1e-4 * 1e-4;
    int n = 0;
    while (e > tgt) { s[n++] = (float)e; e *= ratio; }
    s[n] = (float)tgt;   // n == 114 -> 115 entries total
  }
}

// ---- phase 2a: entire scan, persistent. 512 blocks x 512 threads, C8 in registers. ----
// Block b: q = ((b>>3 & 7)<<3)|(b&7), 128-row chunk = b>>6. Thread: uv[16] = 256 B of C8.
// Inter-step sync: per-family inline barrier (16 blocks cross / 8 diag).
__global__ __launch_bounds__(512, 4) void sink_scan(
    const unsigned char* __restrict__ C8, const float2* __restrict__ rowScale,
    const float* __restrict__ sched, float* pot0, float* pot1, int* __restrict__ famCnt) {
  __shared__ float2 ldsRS[128];
  const int b = blockIdx.x;
  const int x = b & 7, rr = b >> 3;
  const int q = ((rr & 7) << 3) | x;     // XCD swizzle
  const int chunk = b >> 6;              // 0..7 (128-row chunks)
  const int mate = ((q & 7) << 3) | (q >> 3);
  const bool diag = (mate == q);
  const int fam = c_fam[q];
  const int members = diag ? 8 : 16;
  int* fcnt = famCnt + fam;
  const int wave = threadIdx.x >> 6, lane = threadIdx.x & 63;
  const int row0 = chunk << 7;

  if (threadIdx.x < 128)
    ldsRS[threadIdx.x] = rowScale[(q << 10) + row0 + threadIdx.x];

  // load this thread's 16 C-rows (16 B each) ONCE for the whole scan
  const unsigned char* Cb = C8 + ((size_t)q << 20) + ((size_t)row0 << 10) + (lane << 4);
  uint4 uv[16];
#pragma unroll
  for (int k = 0; k < 16; k++)
    uv[k] = *(const uint4*)(Cb + ((size_t)((k << 3) + wave) << 10));
  __syncthreads();

  float* pc = pot0;
  float* pn = pot1;

  for (int st = 0; st < 116; st++) {
    const float eps = sched[st < 115 ? st : 114];
    const bool lse = (eps >= 1e-3f);
    const float cs = (diag && st != 115) ? 0.5f : 0.f;
    const float cm = diag ? ((st == 115) ? 1.f : 0.5f) : 1.f;
    const float c0 = LOG2E / eps;

    const float* hb = pc + (mate << 10) + (lane << 4);
    float h[16];
    {
      float4 h0 = ((const float4*)hb)[0], h1 = ((const float4*)hb)[1];
      float4 h2 = ((const float4*)hb)[2], h3 = ((const float4*)hb)[3];
      h[0]=h0.x; h[1]=h0.y; h[2]=h0.z; h[3]=h0.w;
      h[4]=h1.x; h[5]=h1.y; h[6]=h1.z; h[7]=h1.w;
      h[8]=h2.x; h[9]=h2.y; h[10]=h2.z; h[11]=h2.w;
      h[12]=h3.x; h[13]=h3.y; h[14]=h3.z; h[15]=h3.w;
    }

#pragma unroll
    for (int k = 0; k < 16; k++) {
      const int row = row0 + (k << 3) + wave;
      const float2 rs = ldsRS[(k << 3) + wave];
      const float ns = -rs.y;
      float a[16];
#pragma unroll
      for (int d = 0; d < 4; d++) {
        const unsigned int w = (&uv[k].x)[d];
        a[4 * d + 0] = fmaf(ub(w, 0),  ns, h[4 * d + 0] - rs.x);
        a[4 * d + 1] = fmaf(ub(w, 8),  ns, h[4 * d + 1] - rs.x);
        a[4 * d + 2] = fmaf(ub(w, 16), ns, h[4 * d + 2] - rs.x);
        a[4 * d + 3] = fmaf(ub(w, 24), ns, h[4 * d + 3] - rs.x);
      }
      float m = a[0];
#pragma unroll
      for (int t = 1; t < 16; t++) m = fmaxf(m, a[t]);
      m = wredMax(m);
      float sm;
      if (lse) {
        float ss = 0.f;
#pragma unroll
        for (int t = 0; t < 16; t++) ss += exp2f((a[t] - m) * c0);  // subtract-first
        ss = wredSum(ss);
        sm = -(m + eps * (__logf(ss) - LOG_N));
      } else {
        sm = -m;   // softmin -> min as eps -> 0; |err| <= eps*log n
      }
      if (lane == 0)
        pn[(q << 10) + row] = cs * pc[(q << 10) + row] + cm * sm;
    }

    famsync(fcnt, members * (st + 1));
    float* t = pc; pc = pn; pn = t;
  }
  // 116 steps (even): final potentials land in pot0
}

// ---- phase 2b: per-step fallback (identical math; used only if coop launch fails) ----
template <bool LSE>
__global__ __launch_bounds__(256) void sink_step(
    const unsigned char* __restrict__ C8, const float2* __restrict__ rowScale,
    const float* __restrict__ pot_cur, float* __restrict__ pot_nxt,
    float eps, float csS, float cmS) {
  const int i = blockIdx.x;
  const int x = i & 7, rr = i >> 3;
  const int q = ((rr & 7) << 3) | x;
  const int chunk = rr >> 3;
  const int mate = ((q & 7) << 3) | (q >> 3);
  const bool diag = (mate == q);
  const float cs = diag ? csS : 0.f;
  const float cm = diag ? cmS : 1.f;
  const int wave = threadIdx.x >> 6, lane = threadIdx.x & 63;
  const float* hp = pot_cur + (mate << 10) + (lane << 4);
  float h[16];
  {
    float4 h0 = ((const float4*)hp)[0], h1 = ((const float4*)hp)[1];
    float4 h2 = ((const float4*)hp)[2], h3 = ((const float4*)hp)[3];
    h[0]=h0.x; h[1]=h0.y; h[2]=h0.z; h[3]=h0.w;
    h[4]=h1.x; h[5]=h1.y; h[6]=h1.z; h[7]=h1.w;
    h[8]=h2.x; h[9]=h2.y; h[10]=h2.z; h[11]=h2.w;
    h[12]=h3.x; h[13]=h3.y; h[14]=h3.z; h[15]=h3.w;
  }
  const float c0 = LOG2E / eps;
  const unsigned char* Cb = C8 + ((size_t)q << 20) + ((size_t)chunk << 15) + (lane << 4);
  uint4 uv[8];
#pragma unroll
  for (int k = 0; k < 8; k++)
    uv[k] = *(const uint4*)(Cb + ((size_t)((k << 2) + wave) << 10));
#pragma unroll
  for (int k = 0; k < 8; k++) {
    const int row = (chunk << 5) + (k << 2) + wave;
    const float2 rs = rowScale[(q << 10) + row];
    const float ns = -rs.y;
    float a[16];
#pragma unroll
    for (int d = 0; d < 4; d++) {
      const unsigned int w = (&uv[k].x)[d];
      a[4 * d + 0] = fmaf(ub(w, 0),  ns, h[4 * d + 0] - rs.x);
      a[4 * d + 1] = fmaf(ub(w, 8),  ns, h[4 * d + 1] - rs.x);
      a[4 * d + 2] = fmaf(ub(w, 16), ns, h[4 * d + 2] - rs.x);
      a[4 * d + 3] = fmaf(ub(w, 24), ns, h[4 * d + 3] - rs.x);
    }
    float m = a[0];
#pragma unroll
    for (int t = 1; t < 16; t++) m = fmaxf(m, a[t]);
    m = wredMax(m);
    float sm;
    if (LSE) {
      float ss = 0.f;
#pragma unroll
      for (int t = 0; t < 16; t++) ss += exp2f((a[t] - m) * c0);
      ss = wredSum(ss);
      sm = -(m + eps * (__logf(ss) - LOG_N));
    } else {
      sm = -m;
    }
    if (lane == 0)
      pot_nxt[(q << 10) + row] = cs * pot_cur[(q << 10) + row] + cm * sm;
  }
}

// ---- phase 3: losses ----
__global__ void loss_pairs(const float* __restrict__ pot, float* __restrict__ out) {
  int pb = blockIdx.x;
  int si = c_pa[pb], sj = c_pb[pb];
  const float* fv = pot + ((8 * si + sj) << 10);
  const float* gv = pot + ((8 * sj + si) << 10);
  const float* sa = pot + ((9 * si) << 10);
  const float* sb = pot + ((9 * sj) << 10);
  float acc = 0.f;
  for (int t = threadIdx.x; t < NPT; t += 256)
    acc += (fv[t] - sa[t]) + (gv[t] - sb[t]);
  acc = wredSum(acc);
  __shared__ float wsm[4];
  if ((threadIdx.x & 63) == 0) wsm[threadIdx.x >> 6] = acc;
  __syncthreads();
  if (threadIdx.x == 0) out[1 + pb] = (wsm[0] + wsm[1] + wsm[2] + wsm[3]) * (1.0f / NPT);
}

__global__ void loss_total(float* __restrict__ out) {
  int t = threadIdx.x;
  float x = (t < NPAIR) ? out[1 + t] : 0.f;
  x = wredSum(x);
  if (t == 0) out[0] = x / (float)NPAIR;
}

extern "C" void kernel_launch(void* const* d_in, const int* in_sizes, int n_in,
                              void* d_out, int out_size, void* d_ws, size_t ws_size,
                              hipStream_t stream) {
  const float* feat = (const float*)d_in[0];
  const int* sg = (const int*)d_in[1];
  float* out = (float*)d_out;
  char* ws = (char*)d_ws;

  size_t o = 0;
  __half* Ch = (__half*)(ws + o); o += (size_t)NBLK * NPT * NPT * 2;      // 72 MB (fp16 staging)
  unsigned char* C8 = (unsigned char*)(ws + o); o += (size_t)64 * NPT * NPT; // 64 MB (u8, both orientations)
  float2* rowScale = (float2*)(ws + o); o += (size_t)64 * NPT * 8;        // 512 KB
  float4* pMn = (float4*)(ws + o); o += (size_t)NPAIR * 8 * 256 * 16;     // 0.9 MB
  float4* pMx = (float4*)(ws + o); o += (size_t)NPAIR * 8 * 256 * 16;
  float* G  = (float*)(ws + o); o += (size_t)NROW * DIM * 4;              // 8.4 MB
  float* sq = (float*)(ws + o); o += (size_t)NROW * 4;
  int* idx  = (int*)(ws + o); o += (size_t)NROW * 4;
  int* cnt  = (int*)(ws + o); o += 1024;
  int* famCnt = (int*)(ws + o); o += 256;
  float* schedDev = (float*)(ws + o); o += 512;
  float* pot0 = (float*)(ws + o); o += (size_t)64 * NPT * 4;
  float* pot1 = (float*)(ws + o); o += (size_t)64 * NPT * 4;

  hipMemsetAsync(cnt, 0, 1024, stream);
  hipMemsetAsync(famCnt, 0, 256, stream);
  hipMemsetAsync(pot0, 0, (size_t)64 * NPT * 4, stream);   // f0=g0=s0=0

  build_idx<<<NROW / 256, 256, 0, stream>>>(sg, idx, cnt);
  gather_rows<<<NROW, 256, 0, stream>>>(feat, idx, G, sq);
  cost_gemm<<<NBLK * 64, 256, 0, stream>>>(G, sq, Ch);
  quant_row<<<NBLK * 16, 256, 0, stream>>>(Ch, C8, rowScale);
  colminmax<<<NPAIR * 8, 256, 0, stream>>>(Ch, pMn, pMx);
  colreduce<<<NPAIR, 256, 0, stream>>>(pMn, pMx, rowScale);
  quantT<<<NPAIR * 256, 256, 0, stream>>>(Ch, rowScale, C8);
  sched_init<<<1, 64, 0, stream>>>(schedDev);

  // host copy of the schedule (identical recurrence) for the fallback path
  float sched[256];
  int ns = 0;
  {
    double e = 256.0;
    const double ratio = 0.9 * 0.9;
    const double tgt = 1e-4 * 1e-4;
    while (e > tgt) { sched[ns++] = (float)e; e *= ratio; }
    sched[ns++] = (float)tgt;   // ns == 115
  }
  const float epsT = sched[ns - 1];

  // single persistent launch (cooperative API only for the co-residency guarantee;
  // synchronization is the inline family barrier, NOT cg::grid.sync)
  void* args[] = {(void*)&C8, (void*)&rowScale, (void*)&schedDev,
                  (void*)&pot0, (void*)&pot1, (void*)&famCnt};
  hipError_t cerr = hipLaunchCooperativeKernel((void*)sink_scan, dim3(512), dim3(512),
                                               args, 0, stream);
  if (cerr != hipSuccess) {
    (void)hipGetLastError();   // clear sticky error, fall back to per-step kernels
    float* pp[2] = {pot0, pot1};
    int cur = 0;
    for (int k = 0; k < ns; k++) {
      if (sched[k] >= 1e-3f)
        sink_step<true><<<64 * 32, 256, 0, stream>>>(C8, rowScale, pp[cur], pp[1 - cur],
                                                     sched[k], 0.5f, 0.5f);
      else
        sink_step<false><<<64 * 32, 256, 0, stream>>>(C8, rowScale, pp[cur], pp[1 - cur],
                                                      sched[k], 0.5f, 0.5f);
      cur ^= 1;
    }
    sink_step<false><<<64 * 32, 256, 0, stream>>>(C8, rowScale, pp[cur], pp[1 - cur],
                                                  epsT, 0.0f, 1.0f);
    // 116 launches total -> final potentials in pot0 (same as coop path)
  }

  loss_pairs<<<NPAIR, 256, 0, stream>>>(pot0, out);
  loss_total<<<1, 64, 0, stream>>>(out);
}